// Round 6
// baseline (267.559 us; speedup 1.0000x reference)
//
#include <hip/hip_runtime.h>

#define TOKENS 4096
#define HDIM   1024
#define EDIM   8
#define CAP    1536
#define TAU    0.10f

typedef float f32x4 __attribute__((ext_vector_type(4)));
typedef short bf16x8 __attribute__((ext_vector_type(8)));

static __device__ __forceinline__ unsigned short f2bf(float f) {
    unsigned int u = __float_as_uint(f);
    return (unsigned short)((u + 0x7fffu + ((u >> 16) & 1u)) >> 16);  // RNE
}
static __device__ __forceinline__ unsigned pk(float a, float b) {
    return (unsigned)f2bf(a) | ((unsigned)f2bf(b) << 16);
}

// ---------------- prep: X->bf16, W1->W1T bf16, zero logits/flags, 268MB fill ----------------
// grid 1024x256 = 262144 threads.
__global__ __launch_bounds__(256) void prep_k(
    const float* __restrict__ X, const float* __restrict__ W1,
    unsigned short* __restrict__ Xbf, unsigned short* __restrict__ W1T,
    float* __restrict__ logits, int* __restrict__ flagsnf,
    float* __restrict__ zfill)
{
    const int id = blockIdx.x * 256 + threadIdx.x;

    // X convert: 4096*1024 floats = 524,288 units of 8 floats -> 2 per thread
#pragma unroll
    for (int i = 0; i < 2; i++) {
        const size_t u = (size_t)i * 262144 + id;
        const float* p = X + u * 8;
        float4 a = *(const float4*)(p);
        float4 b = *(const float4*)(p + 4);
        uint4 w;
        w.x = pk(a.x, a.y); w.y = pk(a.z, a.w);
        w.z = pk(b.x, b.y); w.w = pk(b.z, b.w);
        ((uint4*)Xbf)[u] = w;
    }

    // W1 -> W1T (k-contiguous): 131072 threads, one 8-k group each
    if (id < 131072) {
        const int n = id & 1023, kg = id >> 10;   // kg 0..127
        float v[8];
#pragma unroll
        for (int j = 0; j < 8; j++) v[j] = W1[(size_t)(kg * 8 + j) * 1024 + n];
        uint4 w;
        w.x = pk(v[0], v[1]); w.y = pk(v[2], v[3]);
        w.z = pk(v[4], v[5]); w.w = pk(v[6], v[7]);
        ((uint4*)W1T)[(size_t)n * 128 + kg] = w;
    }

    // zero logits (32768 f32 = 8192 f32x4) and flags+nf
    const f32x4 z4 = {0.f, 0.f, 0.f, 0.f};
    if (id < 8192) ((f32x4*)logits)[id] = z4;
    if (id < 9) flagsnf[id] = 0;

    // 268 MB zero-fill: 64 NT stores/thread, fully coalesced (16,777,216 f32x4)
    f32x4* Z = (f32x4*)zfill + id;
#pragma unroll
    for (int i = 0; i < 64; i++)
        __builtin_nontemporal_store(z4, Z + (size_t)i * 262144);
}

// ---------------- fused GEMM: logits += relu(X@W1+b1) @ W2, + 134MB fill ----------------
// Barrier-free: MFMA fragments gathered directly from global bf16 (L1/L2-hot).
// A and B use the IDENTICAL lane->(row,k) map => any HW k-permutation cancels
// (numerics validated in round 4). 512 blocks, 4 waves, wave tile 32x64.
__global__ __launch_bounds__(256) void gemm_fused(
    const unsigned short* __restrict__ Xbf, const unsigned short* __restrict__ W1T,
    const float* __restrict__ b1, const float* __restrict__ W2,
    float* __restrict__ logits, float* __restrict__ zfill2)
{
    const int tid = threadIdx.x;
    const int w = tid >> 6, lane = tid & 63;
    const int g = lane >> 4, r = lane & 15;
    const int m0 = blockIdx.y * 64, n0 = blockIdx.x * 128;
    const int wm = (w >> 1) * 32, wn = (w & 1) * 64;

    const unsigned short* Ap = Xbf + (size_t)(m0 + wm + r) * 1024 + g * 8;
    const unsigned short* Bp = W1T + (size_t)(n0 + wn + r) * 1024 + g * 8;

    const int blk = blockIdx.y * 8 + blockIdx.x;          // 0..511
    f32x4* Z = (f32x4*)zfill2 + (size_t)blk * 256 + tid;  // stride 131072 per store
    const f32x4 z4 = {0.f, 0.f, 0.f, 0.f};

    f32x4 acc[2][4] = {};
    for (int it = 0; it < 32; ++it) {
        const int ko = it * 32;
        bf16x8 af[2], bfr[4];
#pragma unroll
        for (int i = 0; i < 2; i++) af[i]  = *(const bf16x8*)(Ap + i * 16384 + ko);
#pragma unroll
        for (int j = 0; j < 4; j++) bfr[j] = *(const bf16x8*)(Bp + j * 16384 + ko);

        __builtin_nontemporal_store(z4, Z + (size_t)(it * 2 + 0) * 131072);
        __builtin_nontemporal_store(z4, Z + (size_t)(it * 2 + 1) * 131072);

#pragma unroll
        for (int i = 0; i < 2; i++)
#pragma unroll
            for (int j = 0; j < 4; j++)
                acc[i][j] = __builtin_amdgcn_mfma_f32_16x16x32_bf16(af[i], bfr[j], acc[i][j], 0, 0, 0);
    }

    // epilogue: h = relu(acc + b1[col]); plocal[row][e] += h * W2[col][e]
    // D layout (m89-verified): col = wn + j*16 + r, row = wm + i*16 + g*4 + q
    float plocal[8][8];
#pragma unroll
    for (int a = 0; a < 8; a++)
#pragma unroll
        for (int e = 0; e < 8; e++) plocal[a][e] = 0.f;

#pragma unroll
    for (int j = 0; j < 4; j++) {
        const int col = n0 + wn + j * 16 + r;
        const float bias = b1[col];
        float4 w2a = *(const float4*)(W2 + (size_t)col * 8);
        float4 w2b = *(const float4*)(W2 + (size_t)col * 8 + 4);
        float w2v[8] = {w2a.x, w2a.y, w2a.z, w2a.w, w2b.x, w2b.y, w2b.z, w2b.w};
#pragma unroll
        for (int i = 0; i < 2; i++)
#pragma unroll
            for (int q = 0; q < 4; q++) {
                const float h = fmaxf(acc[i][j][q] + bias, 0.f);
#pragma unroll
                for (int e = 0; e < 8; e++)
                    plocal[i * 4 + q][e] = fmaf(h, w2v[e], plocal[i * 4 + q][e]);
            }
    }

    // reduce across the 16 r-lanes of each g-group (cols), then atomic to logits
#pragma unroll
    for (int off = 1; off < 16; off <<= 1)
#pragma unroll
        for (int a = 0; a < 8; a++)
#pragma unroll
            for (int e = 0; e < 8; e++)
                plocal[a][e] += __shfl_xor(plocal[a][e], off);

    if (r == 0) {
#pragma unroll
        for (int i = 0; i < 2; i++)
#pragma unroll
            for (int q = 0; q < 4; q++) {
                const int row = m0 + wm + i * 16 + g * 4 + q;
#pragma unroll
                for (int e = 0; e < 8; e++)
                    atomicAdd(&logits[(size_t)row * 8 + e], plocal[i * 4 + q][e]);
            }
    }
}

// ---------------- router2: softmax/top-3 from logits; flag risky tokens ----------------
__global__ __launch_bounds__(256) void router2_k(
    const float* __restrict__ logits, const float* __restrict__ b2,
    float* __restrict__ probs_out,
    int* __restrict__ e0a, int* __restrict__ e1a,
    float* __restrict__ p0a, float* __restrict__ p1a,
    int* __restrict__ flags, int* __restrict__ nf, int* __restrict__ list)
{
    const int t = blockIdx.x * 256 + threadIdx.x;
    if (t >= TOKENS) return;
    float4 la = *(const float4*)(logits + (size_t)t * 8);
    float4 lb = *(const float4*)(logits + (size_t)t * 8 + 4);
    float logit[8] = {la.x, la.y, la.z, la.w, lb.x, lb.y, lb.z, lb.w};
#pragma unroll
    for (int e = 0; e < 8; e++) logit[e] += b2[e];

    int e0 = 0; float m0 = logit[0];
#pragma unroll
    for (int e = 1; e < 8; e++) if (logit[e] > m0) { m0 = logit[e]; e0 = e; }
    int e1 = -1; float m1 = -1e30f;
#pragma unroll
    for (int e = 0; e < 8; e++) if (e != e0 && logit[e] > m1) { m1 = logit[e]; e1 = e; }
    float m2 = -1e30f;
#pragma unroll
    for (int e = 0; e < 8; e++) if (e != e0 && e != e1 && logit[e] > m2) m2 = logit[e];

    if ((m0 - m1 < TAU) || (m1 - m2 < TAU)) {
        int wdx = atomicAdd(nf, 1);
        list[wdx] = t;                       // exact fp32 recompute later
    } else {
        float p[8], s = 0.f;
#pragma unroll
        for (int e = 0; e < 8; e++) { p[e] = expf(logit[e] - m0); s += p[e]; }
        const float inv = 1.f / s;
#pragma unroll
        for (int e = 0; e < 8; e++) p[e] *= inv;
        float4 pa = {p[0], p[1], p[2], p[3]};
        float4 pb = {p[4], p[5], p[6], p[7]};
        *(float4*)(probs_out + (size_t)t * 8)     = pa;
        *(float4*)(probs_out + (size_t)t * 8 + 4) = pb;
        const float ps = p[e0] + p[e1];
        e0a[t] = e0;
        e1a[t] = e1;
        p0a[t] = p[e0] / ps;
        p1a[t] = p[e1] / ps;
        atomicOr(&flags[e0], 1);
    }
}

// ---------------- exact fp32 recompute of h-rows for flagged tokens ----------------
__global__ __launch_bounds__(256) void rescue_gemm(
    const float* __restrict__ X, const float* __restrict__ W1,
    const float* __restrict__ b1, float* __restrict__ Hout,
    const int* __restrict__ nf, const int* __restrict__ list)
{
    const int n  = nf[0];
    const int i0 = blockIdx.y * 32;
    if (i0 >= n) return;
    const int c0 = blockIdx.x * 128;

    __shared__ float Xs[32][36];
    __shared__ float Ws[32][132];
    __shared__ int   toks[32];
    const int tid = threadIdx.x;
    if (tid < 32) toks[tid] = (i0 + tid < n) ? list[i0 + tid] : list[n - 1];
    __syncthreads();

    const int xi = tid >> 3;
    const int kq = (tid & 7) * 4;
    const int wk = tid >> 3;
    const int cq = (tid & 7) * 16;
    const int to4 = (tid >> 5) * 4;
    const int co4 = (tid & 31) * 4;

    float acc[4][4] = {};
    for (int k0 = 0; k0 < HDIM; k0 += 32) {
        *(float4*)&Xs[xi][kq] = *(const float4*)(X + (size_t)toks[xi] * HDIM + k0 + kq);
        const float* wp = W1 + (size_t)(k0 + wk) * HDIM + c0 + cq;
        *(float4*)&Ws[wk][cq]      = *(const float4*)(wp);
        *(float4*)&Ws[wk][cq + 4]  = *(const float4*)(wp + 4);
        *(float4*)&Ws[wk][cq + 8]  = *(const float4*)(wp + 8);
        *(float4*)&Ws[wk][cq + 12] = *(const float4*)(wp + 12);
        __syncthreads();
#pragma unroll
        for (int kk = 0; kk < 32; kk++) {
            float4 wv = *(const float4*)&Ws[kk][co4];
            float xv[4];
#pragma unroll
            for (int t = 0; t < 4; t++) xv[t] = Xs[to4 + t][kk];
#pragma unroll
            for (int t = 0; t < 4; t++) {
                acc[t][0] = fmaf(xv[t], wv.x, acc[t][0]);
                acc[t][1] = fmaf(xv[t], wv.y, acc[t][1]);
                acc[t][2] = fmaf(xv[t], wv.z, acc[t][2]);
                acc[t][3] = fmaf(xv[t], wv.w, acc[t][3]);
            }
        }
        __syncthreads();
    }
#pragma unroll
    for (int t = 0; t < 4; t++) {
        const size_t row = (size_t)toks[to4 + t] * HDIM;
#pragma unroll
        for (int c = 0; c < 4; c++) {
            const int col = c0 + co4 + c;
            Hout[row + col] = fmaxf(acc[t][c] + b1[col], 0.f);
        }
    }
}

// ---------------- router over rescued tokens (exact fp32 h @ W2) ----------------
__global__ __launch_bounds__(256) void router_pass(
    const float* __restrict__ Hbuf, const float* __restrict__ W2,
    const float* __restrict__ b2, float* __restrict__ probs_out,
    int* __restrict__ e0a, int* __restrict__ e1a,
    float* __restrict__ p0a, float* __restrict__ p1a,
    int* __restrict__ flags, const int* __restrict__ nf, const int* __restrict__ list)
{
    const int wave = threadIdx.x >> 6;
    const int lane = threadIdx.x & 63;
    const int idx  = blockIdx.x * 4 + wave;
    if (idx >= nf[0]) return;
    const int token = list[idx];

    const float* hrow = Hbuf + (size_t)token * HDIM;
    float acc[8] = {0, 0, 0, 0, 0, 0, 0, 0};
#pragma unroll
    for (int k = 0; k < HDIM / 64; k++) {
        const int hidx = lane + (k << 6);
        const float hv = hrow[hidx];
        float4 wa = *(const float4*)(W2 + hidx * 8);
        float4 wb = *(const float4*)(W2 + hidx * 8 + 4);
        acc[0] = fmaf(hv, wa.x, acc[0]);
        acc[1] = fmaf(hv, wa.y, acc[1]);
        acc[2] = fmaf(hv, wa.z, acc[2]);
        acc[3] = fmaf(hv, wa.w, acc[3]);
        acc[4] = fmaf(hv, wb.x, acc[4]);
        acc[5] = fmaf(hv, wb.y, acc[5]);
        acc[6] = fmaf(hv, wb.z, acc[6]);
        acc[7] = fmaf(hv, wb.w, acc[7]);
    }
#pragma unroll
    for (int off = 32; off; off >>= 1)
#pragma unroll
        for (int e = 0; e < 8; e++) acc[e] += __shfl_xor(acc[e], off);

    if (lane == 0) {
        float logit[8];
#pragma unroll
        for (int e = 0; e < 8; e++) logit[e] = acc[e] + b2[e];
        int e0 = 0; float m0 = logit[0];
#pragma unroll
        for (int e = 1; e < 8; e++) if (logit[e] > m0) { m0 = logit[e]; e0 = e; }
        int e1 = -1; float m1 = -1e30f;
#pragma unroll
        for (int e = 0; e < 8; e++) if (e != e0 && logit[e] > m1) { m1 = logit[e]; e1 = e; }

        float p[8], s = 0.f;
#pragma unroll
        for (int e = 0; e < 8; e++) { p[e] = expf(logit[e] - m0); s += p[e]; }
        const float inv = 1.f / s;
#pragma unroll
        for (int e = 0; e < 8; e++) p[e] *= inv;
        float4 pa = {p[0], p[1], p[2], p[3]};
        float4 pb = {p[4], p[5], p[6], p[7]};
        *(float4*)(probs_out + (size_t)token * 8)     = pa;
        *(float4*)(probs_out + (size_t)token * 8 + 4) = pb;
        const float ps = p[e0] + p[e1];
        e0a[token] = e0;
        e1a[token] = e1;
        p0a[token] = p[e0] / ps;
        p1a[token] = p[e1] / ps;
        atomicOr(&flags[e0], 1);
    }
}

// ---------------- scatter dispatch/combine + aux loss (block 0) ----------------
__global__ __launch_bounds__(256) void scatter_aux_k(
    const int* __restrict__ e0a, const int* __restrict__ e1a,
    const float* __restrict__ p0a, const float* __restrict__ p1a,
    const int* __restrict__ flags,
    float* __restrict__ dispatch, float* __restrict__ combine,
    const float* __restrict__ probs, float* __restrict__ auxout)
{
    const int t = blockIdx.x * 256 + threadIdx.x;
    if (t < TOKENS) {
        const int e0 = e0a[t], e1 = e1a[t];
        const size_t b0 = ((size_t)t * EDIM + e0) * CAP;   // round-0 pick -> slot 0
        dispatch[b0] = 1.f;
        combine[b0]  = p0a[t];
        const int s1 = flags[e1] ? 1 : 0;                  // slot 1 iff e1 was anyone's round-0 pick
        const size_t b1 = ((size_t)t * EDIM + e1) * CAP + s1;
        dispatch[b1] = 1.f;
        combine[b1]  = p1a[t];
    }

    if (blockIdx.x == 0) {
        __shared__ float red[4][8];
        const int tid = threadIdx.x, lane = tid & 63, wave = tid >> 6;
        float acc[8] = {0, 0, 0, 0, 0, 0, 0, 0};
        for (int tt = tid; tt < TOKENS; tt += 256) {
            float4 a = *(const float4*)(probs + (size_t)tt * 8);
            float4 b = *(const float4*)(probs + (size_t)tt * 8 + 4);
            acc[0] += a.x; acc[1] += a.y; acc[2] += a.z; acc[3] += a.w;
            acc[4] += b.x; acc[5] += b.y; acc[6] += b.z; acc[7] += b.w;
        }
#pragma unroll
        for (int off = 32; off; off >>= 1)
#pragma unroll
            for (int e = 0; e < 8; e++) acc[e] += __shfl_xor(acc[e], off);
        if (lane == 0)
#pragma unroll
            for (int e = 0; e < 8; e++) red[wave][e] = acc[e];
        __syncthreads();
        if (tid == 0) {
            float aux = 0.f;
#pragma unroll
            for (int e = 0; e < 8; e++) {
                float pe = (red[0][e] + red[1][e] + red[2][e] + red[3][e]) * (1.f / TOKENS);
                aux += pe * logf(pe * (float)EDIM + 1e-9f);
            }
            *auxout = aux;
        }
    }
}

extern "C" void kernel_launch(void* const* d_in, const int* in_sizes, int n_in,
                              void* d_out, int out_size, void* d_ws, size_t ws_size,
                              hipStream_t stream)
{
    const float* X  = (const float*)d_in[0];
    const float* W1 = (const float*)d_in[1];
    const float* b1 = (const float*)d_in[2];
    const float* W2 = (const float*)d_in[3];
    const float* b2 = (const float*)d_in[4];

    float* out = (float*)d_out;
    const size_t dispN = (size_t)TOKENS * EDIM * CAP;   // 50,331,648 floats
    float* dispatch = out;
    float* combine  = out + dispN;
    float* probs    = out + 2 * dispN;
    float* auxout   = out + 2 * dispN + (size_t)TOKENS * EDIM;

    // fill split: prep zeroes first 268,435,456 B of [dispatch|combine], gemm the rest
    float* zfill1 = out;
    float* zfill2 = out + 268435456 / 4;

    // ws layout (<=16.4 MB, round-4-proven footprint):
    //   [0,16MB)  hbuf (fp32 h rows, rescued tokens only)
    //             aliases: Xbf at +0 (8MB), W1T at +8MB (2MB) — both dead before rescue writes hbuf
    //   +16MB     logits (128KB), then small arrays
    char* base = (char*)d_ws;
    float*          hbuf = (float*)base;
    unsigned short* Xbf  = (unsigned short*)base;
    unsigned short* W1T  = (unsigned short*)(base + (8u << 20));
    float*          logits = (float*)(base + (16u << 20));
    char* pp = base + (16u << 20) + (TOKENS * EDIM * sizeof(float));
    int*   e0a  = (int*)pp;   pp += TOKENS * sizeof(int);
    int*   e1a  = (int*)pp;   pp += TOKENS * sizeof(int);
    float* p0a  = (float*)pp; pp += TOKENS * sizeof(float);
    float* p1a  = (float*)pp; pp += TOKENS * sizeof(float);
    int*   flags = (int*)pp;  pp += EDIM * sizeof(int);        // flags[8] + nf contiguous
    int*   nf    = (int*)pp;  pp += sizeof(int);
    int*   list  = (int*)pp;

    prep_k<<<1024, 256, 0, stream>>>(X, W1, Xbf, W1T, logits, flags, zfill1);
    gemm_fused<<<dim3(8, 64), 256, 0, stream>>>(Xbf, W1T, b1, W2, logits, zfill2);
    router2_k<<<16, 256, 0, stream>>>(logits, b2, probs, e0a, e1a, p0a, p1a, flags, nf, list);
    rescue_gemm<<<dim3(8, 128), 256, 0, stream>>>(X, W1, b1, hbuf, nf, list);
    router_pass<<<1024, 256, 0, stream>>>(hbuf, W2, b2, probs, e0a, e1a, p0a, p1a, flags, nf, list);
    scatter_aux_k<<<16, 256, 0, stream>>>(e0a, e1a, p0a, p1a, flags, dispatch, combine, probs, auxout);
}

// Round 7
// 242.520 us; speedup vs baseline: 1.1032x; 1.1032x over previous
//
#include <hip/hip_runtime.h>

#define TOKENS 4096
#define HDIM   1024
#define EDIM   8
#define CAP    1536
#define TAU    0.10f

typedef float f32x4 __attribute__((ext_vector_type(4)));
typedef short bf16x8 __attribute__((ext_vector_type(8)));

static __device__ __forceinline__ unsigned short f2bf(float f) {
    unsigned int u = __float_as_uint(f);
    return (unsigned short)((u + 0x7fffu + ((u >> 16) & 1u)) >> 16);  // RNE
}
static __device__ __forceinline__ unsigned pk(float a, float b) {
    return (unsigned)f2bf(a) | ((unsigned)f2bf(b) << 16);
}

// ---------------- GEMM1 (bf16 MFMA, LDS-staged) + full 402MB zero-fill ----------------
// h = relu(X @ W1 + b1) fp32 out. Tile 128x64, BK=32, 512 blocks = 2/CU.
// A stored [m][k], B stored [n][k] (both k-contiguous, pad 40): identical
// (lane-group -> k) indexing for A and B frags => HW k-permutation cancels
// (numerics proven in R4/R6, absmax 0.0039).
// Fill: 402,653,184 B / 512 blocks = 786,432 B = 49,152 f32x4 = 6/thread/iter.
__global__ __launch_bounds__(256, 2) void gemm_mfma_fill(
    const float* __restrict__ X, const float* __restrict__ W1,
    const float* __restrict__ b1, float* __restrict__ Hout,
    float* __restrict__ zfill, int* __restrict__ flagsnf)
{
    __shared__ unsigned short As[128][40];   // 80B rows: 16B-aligned, ~2-way banks
    __shared__ unsigned short Bs[64][40];
    const int tid  = threadIdx.x;
    const int w    = tid >> 6, lane = tid & 63;
    const int g    = lane >> 4, r = lane & 15;
    const int m0   = blockIdx.y * 128, n0 = blockIdx.x * 64;
    const int wm   = (w >> 1) * 64, wn = (w & 1) * 32;

    const int srow = tid >> 1;           // A stage: row 0..127
    const int soff = (tid & 1) * 16;     // k-offset 0/16
    const int bn   = tid & 63;           // B stage: col 0..63
    const int bko  = (tid >> 6) * 8;     // k-offset 0/8/16/24

    const int blk = blockIdx.y * 16 + blockIdx.x;        // 0..511
    if (blk == 0 && tid < 9) flagsnf[tid] = 0;           // flags[8] + nf
    f32x4* Z = (f32x4*)zfill + (size_t)blk * 49152 + tid;
    const f32x4 z4 = {0.f, 0.f, 0.f, 0.f};

    f32x4 acc[4][2] = {};
    for (int it = 0; it < 32; ++it) {
        const int k0 = it * 32;
        // ---- stage A: 16 f32 -> 16 bf16 -> two b128 LDS writes
        const float* ap = X + (size_t)(m0 + srow) * HDIM + k0 + soff;
        float4 a0 = *(const float4*)(ap);
        float4 a1 = *(const float4*)(ap + 4);
        float4 a2 = *(const float4*)(ap + 8);
        float4 a3 = *(const float4*)(ap + 12);
        uint4 w0, w1;
        w0.x = pk(a0.x, a0.y); w0.y = pk(a0.z, a0.w);
        w0.z = pk(a1.x, a1.y); w0.w = pk(a1.z, a1.w);
        w1.x = pk(a2.x, a2.y); w1.y = pk(a2.z, a2.w);
        w1.z = pk(a3.x, a3.y); w1.w = pk(a3.z, a3.w);
        *(uint4*)&As[srow][soff]     = w0;
        *(uint4*)&As[srow][soff + 8] = w1;

        // ---- stage B transposed: 8 k-strided dword loads (lane-coalesced), one b128 write
        const float* bp = W1 + (size_t)(k0 + bko) * HDIM + n0 + bn;
        float bv[8];
#pragma unroll
        for (int j = 0; j < 8; j++) bv[j] = bp[(size_t)j * HDIM];
        uint4 q;
        q.x = pk(bv[0], bv[1]); q.y = pk(bv[2], bv[3]);
        q.z = pk(bv[4], bv[5]); q.w = pk(bv[6], bv[7]);
        *(uint4*)&Bs[bn][bko] = q;

        // ---- 6 nontemporal zero-stores (ride the vmem pipe; drain = BW floor)
#pragma unroll
        for (int s = 0; s < 6; s++)
            __builtin_nontemporal_store(z4, Z + (size_t)(it * 6 + s) * 256);

        __syncthreads();
        bf16x8 af[4], bfr[2];
#pragma unroll
        for (int i = 0; i < 4; i++) af[i]  = *(const bf16x8*)&As[wm + i * 16 + r][g * 8];
#pragma unroll
        for (int j = 0; j < 2; j++) bfr[j] = *(const bf16x8*)&Bs[wn + j * 16 + r][g * 8];
#pragma unroll
        for (int i = 0; i < 4; i++)
#pragma unroll
            for (int j = 0; j < 2; j++)
                acc[i][j] = __builtin_amdgcn_mfma_f32_16x16x32_bf16(af[i], bfr[j], acc[i][j], 0, 0, 0);
        __syncthreads();
    }

    // epilogue: D col = lane&15 (+16j), row = (lane>>4)*4 + reg  [m89-verified]
#pragma unroll
    for (int j = 0; j < 2; j++) {
        const int col = n0 + wn + j * 16 + r;
        const float bias = b1[col];
#pragma unroll
        for (int i = 0; i < 4; i++) {
            const int row = m0 + wm + i * 16 + g * 4;
#pragma unroll
            for (int q = 0; q < 4; q++)
                Hout[(size_t)(row + q) * HDIM + col] = fmaxf(acc[i][j][q] + bias, 0.f);
        }
    }
}

// ---------------- Router pass (mode 0: all tokens, flag risky; mode 1: rescued only) ----------------
__global__ __launch_bounds__(256) void router_pass(
    const float* __restrict__ Hbuf, const float* __restrict__ W2,
    const float* __restrict__ b2, float* __restrict__ probs_out,
    int* __restrict__ e0a, int* __restrict__ e1a,
    float* __restrict__ p0a, float* __restrict__ p1a,
    int* __restrict__ flags, int* __restrict__ nf, int* __restrict__ list,
    int mode)
{
    const int wave = threadIdx.x >> 6;
    const int lane = threadIdx.x & 63;
    const int idx  = blockIdx.x * 4 + wave;
    int token = idx;
    if (mode == 1) {
        if (idx >= nf[0]) return;
        token = list[idx];
    }

    const float* hrow = Hbuf + (size_t)token * HDIM;
    float acc[8] = {0, 0, 0, 0, 0, 0, 0, 0};
#pragma unroll
    for (int k = 0; k < HDIM / 64; k++) {
        const int hidx = lane + (k << 6);
        const float hv = hrow[hidx];
        float4 wa = *(const float4*)(W2 + hidx * 8);
        float4 wb = *(const float4*)(W2 + hidx * 8 + 4);
        acc[0] = fmaf(hv, wa.x, acc[0]);
        acc[1] = fmaf(hv, wa.y, acc[1]);
        acc[2] = fmaf(hv, wa.z, acc[2]);
        acc[3] = fmaf(hv, wa.w, acc[3]);
        acc[4] = fmaf(hv, wb.x, acc[4]);
        acc[5] = fmaf(hv, wb.y, acc[5]);
        acc[6] = fmaf(hv, wb.z, acc[6]);
        acc[7] = fmaf(hv, wb.w, acc[7]);
    }
#pragma unroll
    for (int off = 32; off; off >>= 1)
#pragma unroll
        for (int e = 0; e < 8; e++) acc[e] += __shfl_xor(acc[e], off);

    if (lane == 0) {
        float logit[8];
#pragma unroll
        for (int e = 0; e < 8; e++) logit[e] = acc[e] + b2[e];
        // top-3 (strict > => ties to lower index, matches lax.top_k)
        int e0 = 0; float m0 = logit[0];
#pragma unroll
        for (int e = 1; e < 8; e++) if (logit[e] > m0) { m0 = logit[e]; e0 = e; }
        int e1 = -1; float m1 = -1e30f;
#pragma unroll
        for (int e = 0; e < 8; e++) if (e != e0 && logit[e] > m1) { m1 = logit[e]; e1 = e; }
        float m2 = -1e30f;
#pragma unroll
        for (int e = 0; e < 8; e++) if (e != e0 && e != e1 && logit[e] > m2) m2 = logit[e];

        if (mode == 0 && ((m0 - m1 < TAU) || (m1 - m2 < TAU))) {
            int wdx = atomicAdd(nf, 1);
            list[wdx] = token;            // defer to exact fp32 recompute
        } else {
            float p[8], s = 0.f;
#pragma unroll
            for (int e = 0; e < 8; e++) { p[e] = expf(logit[e] - m0); s += p[e]; }
            const float inv = 1.f / s;
#pragma unroll
            for (int e = 0; e < 8; e++) p[e] *= inv;
            float4 pa = {p[0], p[1], p[2], p[3]};
            float4 pb = {p[4], p[5], p[6], p[7]};
            *(float4*)(probs_out + (size_t)token * 8)     = pa;
            *(float4*)(probs_out + (size_t)token * 8 + 4) = pb;
            const float ps = p[e0] + p[e1];
            e0a[token] = e0;
            e1a[token] = e1;
            p0a[token] = p[e0] / ps;
            p1a[token] = p[e1] / ps;
            atomicOr(&flags[e0], 1);
        }
    }
}

// ---------------- exact fp32 recompute of h-rows for flagged tokens ----------------
__global__ __launch_bounds__(256) void rescue_gemm(
    const float* __restrict__ X, const float* __restrict__ W1,
    const float* __restrict__ b1, float* __restrict__ Hout,
    const int* __restrict__ nf, const int* __restrict__ list)
{
    const int n  = nf[0];
    const int i0 = blockIdx.y * 32;
    if (i0 >= n) return;
    const int c0 = blockIdx.x * 128;

    __shared__ float Xs[32][36];
    __shared__ float Ws[32][132];
    __shared__ int   toks[32];
    const int tid = threadIdx.x;
    if (tid < 32) toks[tid] = (i0 + tid < n) ? list[i0 + tid] : list[n - 1];
    __syncthreads();

    const int xi = tid >> 3;
    const int kq = (tid & 7) * 4;
    const int wk = tid >> 3;
    const int cq = (tid & 7) * 16;
    const int to4 = (tid >> 5) * 4;
    const int co4 = (tid & 31) * 4;

    float acc[4][4] = {};
    for (int k0 = 0; k0 < HDIM; k0 += 32) {
        *(float4*)&Xs[xi][kq] = *(const float4*)(X + (size_t)toks[xi] * HDIM + k0 + kq);
        const float* wp = W1 + (size_t)(k0 + wk) * HDIM + c0 + cq;
        *(float4*)&Ws[wk][cq]      = *(const float4*)(wp);
        *(float4*)&Ws[wk][cq + 4]  = *(const float4*)(wp + 4);
        *(float4*)&Ws[wk][cq + 8]  = *(const float4*)(wp + 8);
        *(float4*)&Ws[wk][cq + 12] = *(const float4*)(wp + 12);
        __syncthreads();
#pragma unroll
        for (int kk = 0; kk < 32; kk++) {
            float4 wv = *(const float4*)&Ws[kk][co4];
            float xv[4];
#pragma unroll
            for (int t = 0; t < 4; t++) xv[t] = Xs[to4 + t][kk];
#pragma unroll
            for (int t = 0; t < 4; t++) {
                acc[t][0] = fmaf(xv[t], wv.x, acc[t][0]);
                acc[t][1] = fmaf(xv[t], wv.y, acc[t][1]);
                acc[t][2] = fmaf(xv[t], wv.z, acc[t][2]);
                acc[t][3] = fmaf(xv[t], wv.w, acc[t][3]);
            }
        }
        __syncthreads();
    }
#pragma unroll
    for (int t = 0; t < 4; t++) {
        const size_t row = (size_t)toks[to4 + t] * HDIM;
#pragma unroll
        for (int c = 0; c < 4; c++) {
            const int col = c0 + co4 + c;
            Hout[row + col] = fmaxf(acc[t][c] + b1[col], 0.f);
        }
    }
}

// ---------------- scatter dispatch/combine + aux loss (block 0) ----------------
__global__ __launch_bounds__(256) void scatter_aux_k(
    const int* __restrict__ e0a, const int* __restrict__ e1a,
    const float* __restrict__ p0a, const float* __restrict__ p1a,
    const int* __restrict__ flags,
    float* __restrict__ dispatch, float* __restrict__ combine,
    const float* __restrict__ probs, float* __restrict__ auxout)
{
    const int t = blockIdx.x * 256 + threadIdx.x;
    if (t < TOKENS) {
        const int e0 = e0a[t], e1 = e1a[t];
        const size_t b0 = ((size_t)t * EDIM + e0) * CAP;   // round-0 pick -> slot 0
        dispatch[b0] = 1.f;
        combine[b0]  = p0a[t];
        const int s1 = flags[e1] ? 1 : 0;                  // slot 1 iff e1 was anyone's round-0 pick
        const size_t b1 = ((size_t)t * EDIM + e1) * CAP + s1;
        dispatch[b1] = 1.f;
        combine[b1]  = p1a[t];
    }

    if (blockIdx.x == 0) {
        __shared__ float red[4][8];
        const int tid = threadIdx.x, lane = tid & 63, wave = tid >> 6;
        float acc[8] = {0, 0, 0, 0, 0, 0, 0, 0};
        for (int tt = tid; tt < TOKENS; tt += 256) {
            float4 a = *(const float4*)(probs + (size_t)tt * 8);
            float4 b = *(const float4*)(probs + (size_t)tt * 8 + 4);
            acc[0] += a.x; acc[1] += a.y; acc[2] += a.z; acc[3] += a.w;
            acc[4] += b.x; acc[5] += b.y; acc[6] += b.z; acc[7] += b.w;
        }
#pragma unroll
        for (int off = 32; off; off >>= 1)
#pragma unroll
            for (int e = 0; e < 8; e++) acc[e] += __shfl_xor(acc[e], off);
        if (lane == 0)
#pragma unroll
            for (int e = 0; e < 8; e++) red[wave][e] = acc[e];
        __syncthreads();
        if (tid == 0) {
            float aux = 0.f;
#pragma unroll
            for (int e = 0; e < 8; e++) {
                float pe = (red[0][e] + red[1][e] + red[2][e] + red[3][e]) * (1.f / TOKENS);
                aux += pe * logf(pe * (float)EDIM + 1e-9f);
            }
            *auxout = aux;
        }
    }
}

extern "C" void kernel_launch(void* const* d_in, const int* in_sizes, int n_in,
                              void* d_out, int out_size, void* d_ws, size_t ws_size,
                              hipStream_t stream)
{
    const float* X  = (const float*)d_in[0];
    const float* W1 = (const float*)d_in[1];
    const float* b1 = (const float*)d_in[2];
    const float* W2 = (const float*)d_in[3];
    const float* b2 = (const float*)d_in[4];

    float* out = (float*)d_out;
    const size_t dispN = (size_t)TOKENS * EDIM * CAP;   // 50,331,648 floats
    float* dispatch = out;
    float* combine  = out + dispN;
    float* probs    = out + 2 * dispN;
    float* auxout   = out + 2 * dispN + (size_t)TOKENS * EDIM;

    // ws layout: hbuf fp32 h (16MB), then small arrays
    char* base = (char*)d_ws;
    float* hbuf = (float*)base;
    char* pp = base + (size_t)TOKENS * HDIM * sizeof(float);
    int*   e0a  = (int*)pp;   pp += TOKENS * sizeof(int);
    int*   e1a  = (int*)pp;   pp += TOKENS * sizeof(int);
    float* p0a  = (float*)pp; pp += TOKENS * sizeof(float);
    float* p1a  = (float*)pp; pp += TOKENS * sizeof(float);
    int*   flags = (int*)pp;  pp += EDIM * sizeof(int);   // flags[8] + nf contiguous
    int*   nf    = (int*)pp;  pp += sizeof(int);
    int*   list  = (int*)pp;

    // gemm fills ALL of dispatch+combine (402MB) + writes h + zeroes flags/nf
    gemm_mfma_fill<<<dim3(16, 32), 256, 0, stream>>>(X, W1, b1, hbuf, dispatch, flags);
    router_pass<<<TOKENS / 4, 256, 0, stream>>>(hbuf, W2, b2, probs,
                                                e0a, e1a, p0a, p1a, flags, nf, list, 0);
    rescue_gemm<<<dim3(8, 128), 256, 0, stream>>>(X, W1, b1, hbuf, nf, list);
    router_pass<<<TOKENS / 4, 256, 0, stream>>>(hbuf, W2, b2, probs,
                                                e0a, e1a, p0a, p1a, flags, nf, list, 1);
    scatter_aux_k<<<16, 256, 0, stream>>>(e0a, e1a, p0a, p1a, flags, dispatch, combine, probs, auxout);
}